// Round 1
// baseline (15.650 us; speedup 1.0000x reference)
//
#include <hip/hip_runtime.h>

// PrRoIPool (Precise RoI Pooling), forward only.
// features: [B=2, C=64, H=100, W=100] f32
// rois:     [N=256, 5] f32  (bidx, x1, y1, x2, y2) in image coords
// out:      [N, C, 7, 7] f32
//
// Each bin integrates the bilinearly-interpolated feature map over the bin
// rectangle; separable into per-axis hat-kernel integrals (cdf differences).
// Setup guarantees scaled ROI span <= 40 px -> bin width bw <= 40/7 < 5.72,
// so per-axis support (u0-1, u1+1) covers at most 8 integer pixels. We use a
// fixed 8x8 window whose start is clamped to [0, dim-8]; out-of-support
// pixels get exactly-zero weights, so this is exact and branch-free.

constexpr int OUT_H = 7, OUT_W = 7;
constexpr float SPATIAL_SCALE = 0.25f;
constexpr int CH = 64, FH = 100, FW = 100;
constexpr int SUP = 8;  // max pixels of support per axis (bw+2 < 8)

__device__ __forceinline__ float hat_cdf(float t) {
    // Antiderivative of max(0, 1-|s|) evaluated at t.
    float a = fminf(fmaxf(t + 1.0f, 0.0f), 1.0f);
    float b = fminf(fmaxf(1.0f - t, 0.0f), 1.0f);
    return (t < 0.0f) ? 0.5f * a * a : 1.0f - 0.5f * b * b;
}

__global__ __launch_bounds__(256) void prroi_pool_kernel(
    const float* __restrict__ feat, const float* __restrict__ rois,
    float* __restrict__ out, int n_rois) {
    int idx = blockIdx.x * 256 + threadIdx.x;
    int total = n_rois * CH * OUT_H * OUT_W;
    if (idx >= total) return;

    int q = idx % OUT_W;
    int p = (idx / OUT_W) % OUT_H;
    int c = (idx / (OUT_W * OUT_H)) % CH;
    int n = idx / (OUT_W * OUT_H * CH);

    const float* r = rois + n * 5;
    int b = (int)r[0];
    float x1 = r[1] * SPATIAL_SCALE;
    float y1 = r[2] * SPATIAL_SCALE;
    float x2 = r[3] * SPATIAL_SCALE;
    float y2 = r[4] * SPATIAL_SCALE;
    float bw = fmaxf(x2 - x1, 0.0f) * (1.0f / OUT_W);
    float bh = fmaxf(y2 - y1, 0.0f) * (1.0f / OUT_H);

    // Bin edges in feature-pixel coords.
    float u0x = x1 + (float)q * bw, u1x = u0x + bw;
    float u0y = y1 + (float)p * bh, u1y = u0y + bh;

    // Fixed-size window start, clamped so all SUP pixels are in-bounds.
    // Support-in-image is always contained in [start, start+SUP-1]
    // (support length < SUP, and clamping only happens at image edges).
    int ws = min(max((int)ceilf(u0x - 1.0f), 0), FW - SUP);
    int hs = min(max((int)ceilf(u0y - 1.0f), 0), FH - SUP);

    float wx[SUP], wy[SUP];
#pragma unroll
    for (int j = 0; j < SUP; ++j) {
        float px = (float)(ws + j);
        wx[j] = hat_cdf(u1x - px) - hat_cdf(u0x - px);
        float py = (float)(hs + j);
        wy[j] = hat_cdf(u1y - py) - hat_cdf(u0y - py);
    }

    const float* fb = feat + ((b * CH + c) * FH + hs) * FW + ws;
    float acc = 0.0f;
#pragma unroll
    for (int i = 0; i < SUP; ++i) {
        const float* row = fb + i * FW;
        float rs = 0.0f;
#pragma unroll
        for (int j = 0; j < SUP; ++j) rs = fmaf(wx[j], row[j], rs);
        acc = fmaf(wy[i], rs, acc);
    }

    float area = bw * bh;
    out[idx] = (area > 0.0f) ? acc / fmaxf(area, 1e-12f) : 0.0f;
}

extern "C" void kernel_launch(void* const* d_in, const int* in_sizes, int n_in,
                              void* d_out, int out_size, void* d_ws, size_t ws_size,
                              hipStream_t stream) {
    const float* feat = (const float*)d_in[0];
    const float* rois = (const float*)d_in[1];
    float* out = (float*)d_out;
    int n_rois = in_sizes[1] / 5;
    int total = n_rois * CH * OUT_H * OUT_W;
    int blocks = (total + 255) / 256;
    hipLaunchKernelGGL(prroi_pool_kernel, dim3(blocks), dim3(256), 0, stream,
                       feat, rois, out, n_rois);
}